// Round 8
// baseline (167.115 us; speedup 1.0000x reference)
//
#include <hip/hip_runtime.h>

#define B_ 8
#define M_ 32
#define C_ 512
#define H_ 64
#define W_ 64
#define HW 4096
#define NKT 16
#define KC 32
// gcm tile
#define TW 4
#define TH 4
#define NPOS 16
#define PW 6
#define PH 6
#define NPM 36
// padded m grid
#define HP 66
#define WP 66
#define HPWP (HP*WP)

typedef __attribute__((ext_vector_type(8))) short short8;
typedef __attribute__((ext_vector_type(4))) float float4v;

static __device__ __forceinline__ unsigned pk_bf16(float lo, float hi) {
    unsigned r;
    asm("v_cvt_pk_bf16_f32 %0, %1, %2" : "=v"(r) : "v"(lo), "v"(hi));
    return r;
}

static __device__ __forceinline__ void load_lds16(const short* g, short* l) {
    __builtin_amdgcn_global_load_lds((const __attribute__((address_space(1))) void*)g,
                                     (__attribute__((address_space(3))) void*)l, 16, 0, 0);
}

// ---------- zero the norm-accumulator buffers (re-run every launch) ----------
__global__ void zero_norms(float* __restrict__ p) {
    int i = blockIdx.x * 256 + threadIdx.x;          // 160*256*4 = 163840 floats
    ((float4v*)p)[i] = (float4v){0.f, 0.f, 0.f, 0.f};
}

// ---------- prep v5: h-quad (1KB read runs) x c-split (TLP), dbuf chunks ----------
// blocks 0..255   : q (pr = g>>6 of 4,  hq = (g>>2)&15, ktg = g&3)
// blocks 256..1279: m (pr of 16, hq, ktg)
__global__ __launch_bounds__(512)
void prep_kernel(const float* __restrict__ Q, const float* __restrict__ Mb,
                 short* __restrict__ qT, short* __restrict__ mT,
                 float* __restrict__ nq, float* __restrict__ nm) {
    __shared__ unsigned buf[2][8704];   // 2 x 34816 B; slab (row*2+img)*1088 + w*17 + cpair

    const int tid = threadIdx.x;
    const bool isq = (blockIdx.x < 256);
    const int g  = isq ? (int)blockIdx.x : (int)blockIdx.x - 256;
    const int pr  = g >> 6;
    const int hq  = (g >> 2) & 15;
    const int ktg = g & 3;
    const float* base = (isq ? Q : Mb) + (size_t)(pr * 2) * C_ * HW;

    // load/LDS-write roles
    const int w4 = tid & 15, cpr = (tid >> 4) & 15, limg = tid >> 8;
    const float* lsrc = base + (size_t)limg * C_ * HW
                      + (size_t)(ktg * 128 + cpr * 2) * HW
                      + (size_t)(hq * 4) * W_ + w4 * 4;

    // LDS-gather / global-store roles
    const int rw = tid & 63, rr2 = (tid >> 6) & 3, rim = tid >> 8;
    const unsigned* rb0 = &buf[0][(rr2 * 2 + rim) * 1088 + rw * 17];
    const unsigned* rb1 = &buf[1][(rr2 * 2 + rim) * 1088 + rw * 17];

    float4v s0 = {0.f,0.f,0.f,0.f}, s1 = s0, s2 = s0, s3 = s0;
    float4v A0, A1, A2, A3, B0, B1, B2, B3;

#define LOADP(ch) { const float* p_ = lsrc + (size_t)(ch) * 32 * HW; \
    A0 = *(const float4v*)(p_);       A1 = *(const float4v*)(p_ + 64); \
    A2 = *(const float4v*)(p_ + 128); A3 = *(const float4v*)(p_ + 192); \
    const float* q_ = p_ + HW; \
    B0 = *(const float4v*)(q_);       B1 = *(const float4v*)(q_ + 64); \
    B2 = *(const float4v*)(q_ + 128); B3 = *(const float4v*)(q_ + 192); }

#define WRITEP(bs) { unsigned* w_ = &buf[bs][limg * 1088 + cpr]; \
    s0 += A0 * A0 + B0 * B0; s1 += A1 * A1 + B1 * B1; \
    s2 += A2 * A2 + B2 * B2; s3 += A3 * A3 + B3 * B3; \
    _Pragma("unroll") \
    for (int j = 0; j < 4; ++j) { \
        w_[0 * 2176 + (w4 * 4 + j) * 17] = pk_bf16(A0[j], B0[j]); \
        w_[1 * 2176 + (w4 * 4 + j) * 17] = pk_bf16(A1[j], B1[j]); \
        w_[2 * 2176 + (w4 * 4 + j) * 17] = pk_bf16(A2[j], B2[j]); \
        w_[3 * 2176 + (w4 * 4 + j) * 17] = pk_bf16(A3[j], B3[j]); } }

#define STOREP(ch, rb) { union { unsigned u[16]; short8 v[4]; } o_; \
    _Pragma("unroll") \
    for (int q_i = 0; q_i < 16; ++q_i) o_.u[q_i] = (rb)[q_i]; \
    short* d_; \
    if (isq) d_ = qT + (((size_t)(ktg * 4 + (ch)) * HW + (size_t)(hq * 4 + rr2) * 64 + rw) * B_ \
                        + pr * 2 + rim) * KC; \
    else     d_ = mT + (((size_t)(ktg * 4 + (ch)) * HPWP + (size_t)(hq * 4 + rr2 + 1) * WP + rw + 1) * M_ \
                        + pr * 2 + rim) * KC; \
    *(short8*)(d_)      = o_.v[0]; *(short8*)(d_ + 8)  = o_.v[1]; \
    *(short8*)(d_ + 16) = o_.v[2]; *(short8*)(d_ + 24) = o_.v[3]; }

    LOADP(0); WRITEP(0); __syncthreads();
    LOADP(1); STOREP(0, rb0); WRITEP(1); __syncthreads();
    LOADP(2); STOREP(1, rb1); WRITEP(0); __syncthreads();
    LOADP(3); STOREP(2, rb0); WRITEP(1); __syncthreads();
    STOREP(3, rb1);

    // ---- norms: per-row partials -> LDS (buf0, disjoint from buf1 reads) -> atomic ----
    float* redf = (float*)&buf[0][0];   // 8192 floats = 32 KB
    *(float4v*)&redf[(((cpr * 2 + limg) * 4 + 0) * 16 + w4) * 4] = s0;
    *(float4v*)&redf[(((cpr * 2 + limg) * 4 + 1) * 16 + w4) * 4] = s1;
    *(float4v*)&redf[(((cpr * 2 + limg) * 4 + 2) * 16 + w4) * 4] = s2;
    *(float4v*)&redf[(((cpr * 2 + limg) * 4 + 3) * 16 + w4) * 4] = s3;
    __syncthreads();
    {
        float t = 0.f;
        #pragma unroll
        for (int cp = 0; cp < 16; ++cp)
            t += redf[(((cp * 2 + rim) * 4 + rr2) * 16 + (rw >> 2)) * 4 + (rw & 3)];
        atomicAdd(&(isq ? nq : nm)[(size_t)(pr * 2 + rim) * HW + (size_t)(hq * 4 + rr2) * 64 + rw], t);
    }

    // ---- m-blocks: zero halo-ring slices (this block's rows/kts, its pr 128B slice) ----
    if (!isq) {
        short8 z = (short8){0, 0, 0, 0, 0, 0, 0, 0};
        if (tid < 256) {            // cols 0 & 65, rows hq*4+1..+4, kts ktg*4..+3
            int e = tid & 7, cell = tid >> 3;
            int kk = cell & 3, rr = (cell >> 2) & 3, cs = cell >> 4;
            size_t pos2 = (size_t)(hq * 4 + 1 + rr) * WP + (cs ? 65 : 0);
            *(short8*)(mT + (((size_t)(ktg * 4 + kk) * HPWP + pos2) * M_ + pr * 2) * KC + e * 8) = z;
        }
        if (hq == 0 || hq == 15) {  // full pad rows 0 / 65 for this ktg
            int row = (hq == 0) ? 0 : 65;
            for (int j = tid; j < 66 * 4 * 8; j += 512) {
                int e = j & 7, cell = j >> 3;
                int kk = cell & 3, col = cell >> 2;
                *(short8*)(mT + (((size_t)(ktg * 4 + kk) * HPWP + (size_t)row * WP + col) * M_ + pr * 2) * KC
                           + e * 8) = z;
            }
        }
    }
#undef LOADP
#undef WRITEP
#undef STOREP
}

// ---------- gcm: MFMA on raw bf16, rsqrt-scaled epilogue (unchanged) ----------
__global__ __launch_bounds__(1024)
void gcm_kernel(const short* __restrict__ qT, const short* __restrict__ mT,
                const float* __restrict__ nq, const float* __restrict__ nm,
                float* __restrict__ out) {
    __shared__ __align__(16) short m_lds[NPM * M_ * KC];   // 72 KB
    __shared__ __align__(16) short q_lds[NPOS * 16 * KC];  // 16 KB

    const int tid = threadIdx.x;
    const int bx = blockIdx.x & 15, by = blockIdx.x >> 4;
    const int w0 = bx * TW, h0 = by * TH;
    const int wid = tid >> 6, lane = tid & 63;
    const int lw = wid & 3, lh = wid >> 2;
    const int col = lane & 15, kg = lane >> 4;
    const int mypos = lh * TW + lw;
    const int gh = h0 + lh, gw = w0 + lw;

    {
        short8 z = (short8){0, 0, 0, 0, 0, 0, 0, 0};
        *(short8*)&q_lds[tid * 8] = z;
    }

    float4v acc[9][2];
    #pragma unroll
    for (int d = 0; d < 9; ++d)
        #pragma unroll
        for (int hf = 0; hf < 2; ++hf)
            acc[d][hf] = (float4v){0.f, 0.f, 0.f, 0.f};

    for (int kt = 0; kt < NKT; ++kt) {
        __syncthreads();
        if (tid < 512) {
            int chunk = tid & 3, b = (tid >> 2) & 7, pidx = tid >> 5;
            int qh = h0 + (pidx >> 2), qw = w0 + (pidx & 3);
            const short* src = qT + (((size_t)kt * HW + qh * W_ + qw) * B_ + b) * KC + chunk * 8;
            *(short8*)&q_lds[pidx * 512 + b * KC + chunk * 8] = *(const short8*)src;
        }
        for (int j = wid; j < NPM * 2; j += 16) {
            int pm = j >> 1, half = j & 1;
            int ph = pm / PW, pw = pm % PW;
            size_t pos2 = (size_t)(h0 + ph) * WP + (w0 + pw);
            const short* gsrc = mT + ((size_t)kt * HPWP + pos2) * (M_ * KC)
                              + half * 512 + (size_t)lane * 8;
            short* ldst = m_lds + pm * 1024 + half * 512;
            load_lds16(gsrc, ldst);
        }
        __syncthreads();
        short8 aq = *(const short8*)&q_lds[mypos * 512 + col * KC + kg * 8];
        #pragma unroll
        for (int dh = 0; dh < 3; ++dh)
            #pragma unroll
            for (int dw = 0; dw < 3; ++dw) {
                const int pm = (lh + dh) * PW + (lw + dw);
                #pragma unroll
                for (int hf = 0; hf < 2; ++hf) {
                    short8 bm = *(const short8*)&m_lds[pm * 1024 + (hf * 16 + col) * KC + kg * 8];
                    acc[dh * 3 + dw][hf] =
                        __builtin_amdgcn_mfma_f32_16x16x32_bf16(aq, bm, acc[dh * 3 + dw][hf], 0, 0, 0);
                }
            }
    }

    float iq[4];
    #pragma unroll
    for (int r = 0; r < 4; ++r) {
        float ss = nq[(size_t)((kg & 1) * 4 + r) * HW + gh * W_ + gw];
        iq[r] = 1.0f / fmaxf(sqrtf(ss), 1e-12f);
    }
    float im[2][9];
    #pragma unroll
    for (int dh = 0; dh < 3; ++dh)
        #pragma unroll
        for (int dw = 0; dw < 3; ++dw) {
            int hh = min(63, max(0, gh + dh - 1));
            int ww = min(63, max(0, gw + dw - 1));
            #pragma unroll
            for (int hf = 0; hf < 2; ++hf) {
                float ss = nm[(size_t)(hf * 16 + col) * HW + hh * W_ + ww];
                im[hf][dh * 3 + dw] = 1.0f / fmaxf(sqrtf(ss), 1e-12f);
            }
        }
    float res[4];
    #pragma unroll
    for (int r = 0; r < 4; ++r) {
        float v0 = -1e30f, v1 = -1e30f;
        #pragma unroll
        for (int d = 0; d < 9; ++d) {
            v0 = fmaxf(v0, acc[d][0][r] * im[0][d]);
            v1 = fmaxf(v1, acc[d][1][r] * im[1][d]);
        }
        res[r] = fmaxf(v0 * iq[r], 0.f) + fmaxf(v1 * iq[r], 0.f);
    }
    #pragma unroll
    for (int mask = 1; mask < 16; mask <<= 1)
        #pragma unroll
        for (int r = 0; r < 4; ++r)
            res[r] += __shfl_xor(res[r], mask);

    if (col == 0 && kg < 2) {
        #pragma unroll
        for (int r = 0; r < 4; ++r) {
            int b = kg * 4 + r;
            out[(size_t)b * HW + gh * W_ + gw] = 1.0f - res[r] * (1.0f / M_);
        }
    }
}

extern "C" void kernel_launch(void* const* d_in, const int* in_sizes, int n_in,
                              void* d_out, int out_size, void* d_ws, size_t ws_size,
                              hipStream_t stream) {
    const float* Q  = (const float*)d_in[0];
    const float* Mb = (const float*)d_in[1];
    float* out = (float*)d_out;

    const size_t MT_SHORTS = (size_t)NKT * HPWP * M_ * KC;   // 71,368,704
    const size_t QT_SHORTS = (size_t)NKT * HW * B_ * KC;     // 16,777,216
    short* mT = (short*)d_ws;
    short* qT = mT + MT_SHORTS;
    float* nq = (float*)(qT + QT_SHORTS);
    float* nm = nq + B_ * HW;

    zero_norms<<<160, 256, 0, stream>>>(nq);                 // nq+nm contiguous 163840 f32
    prep_kernel<<<1280, 512, 0, stream>>>(Q, Mb, qT, mT, nq, nm);
    gcm_kernel<<<256, 1024, 0, stream>>>(qT, mT, nq, nm, out);
}